// Round 4
// baseline (520.129 us; speedup 1.0000x reference)
//
#include <hip/hip_runtime.h>

#define N_NODES 50000
#define N_EDGES 800000
#define HID 128

typedef _Float16 f16;
typedef _Float16 half8 __attribute__((ext_vector_type(8)));
typedef _Float16 half4 __attribute__((ext_vector_type(4)));
typedef float f32x4 __attribute__((ext_vector_type(4)));

// ---- CSR-path workspace layout (bytes) ----
#define OFF_MEDGE  0UL             // 800000*128*2 = 204,800,000  (CSR-ordered gated messages)
#define OFF_H16C   204800000UL     // 12,800,000
#define OFF_WC     217600000UL     // packed weights: 204,800
#define OFF_CNT    217804800UL     // 50176*4 = 200,704
#define OFF_OFFS   218005504UL     // 200,704
#define OFF_CUR    218206208UL     // 200,704
#define OFF_BSUM   218406912UL     // 1,024
#define OFF_ELIST  218407936UL     // 3,200,000
#define CSR_TOTAL  221607936UL

// ---- fallback (atomic-path) layout ----
#define OFF_MI   0UL
#define OFF_H16  25600000UL
#define OFF_W    38400000UL

#define WB1 0
#define WB2 36864
#define WN1 53248
#define WN2 86016

#define XS 296   // X tile stride (f16): 128 hdst | 128 hsrc | 24 attr | 8 zero | 8 unused
#define TS 136   // T tile stride (aliased into X buffer)
#define YS 264   // node Y tile stride (256 + pad)

__global__ __launch_bounds__(256) void pack_weights(
    const float* __restrict__ We1, const float* __restrict__ We2,
    const float* __restrict__ Wn1, const float* __restrict__ Wn2,
    f16* __restrict__ W) {
  int i = blockIdx.x * 256 + threadIdx.x;   // 0..102399
  if (i < 36864) {                          // We1 (rows permuted: h first, attr last)
    int j = i & 7, n = (i >> 3) & 127, qk = i >> 10;
    int k = qk * 8 + j;
    float v = 0.f;
    if (k < 256) v = We1[(24 + k) * 128 + n];
    else if (k < 280) v = We1[(k - 256) * 128 + n];
    W[WB1 + i] = (f16)v;
  } else if (i < 53248) {                   // We2
    int l = i - 36864;
    int j = l & 7, n = (l >> 3) & 127, qk = l >> 10;
    W[WB2 + l] = (f16)We2[(qk * 8 + j) * 128 + n];
  } else if (i < 86016) {                   // Wn1
    int l = i - 53248;
    int j = l & 7, n = (l >> 3) & 127, qk = l >> 10;
    W[WN1 + l] = (f16)Wn1[(qk * 8 + j) * 128 + n];
  } else if (i < 102400) {                  // Wn2
    int l = i - 86016;
    int j = l & 7, n = (l >> 3) & 127, qk = l >> 10;
    W[WN2 + l] = (f16)Wn2[(qk * 8 + j) * 128 + n];
  }
}

__global__ __launch_bounds__(256) void convert_h(const float* __restrict__ h, f16* __restrict__ h16) {
  int i = blockIdx.x * 256 + threadIdx.x;
  const float4* src = (const float4*)h + (size_t)i * 2;
  float4 a = src[0], b = src[1];
  half8 v = {(f16)a.x, (f16)a.y, (f16)a.z, (f16)a.w,
             (f16)b.x, (f16)b.y, (f16)b.z, (f16)b.w};
  *((half8*)h16 + i) = v;
}

// ==== CSR build ====
__global__ __launch_bounds__(256) void hist_kernel(const int* __restrict__ eidx, int* __restrict__ cnt) {
  int e = blockIdx.x * 256 + threadIdx.x;
  if (e < N_EDGES) atomicAdd(&cnt[eidx[e]], 1);
}

__global__ __launch_bounds__(256) void scan1_kernel(const int* __restrict__ cnt,
                                                    int* __restrict__ offs, int* __restrict__ bsum) {
  __shared__ int sb[256];
  int t = threadIdx.x, base = blockIdx.x * 1024;
  int c[4];
  int s4 = 0;
  #pragma unroll
  for (int k = 0; k < 4; ++k) { c[k] = cnt[base + t * 4 + k]; s4 += c[k]; }
  sb[t] = s4;
  __syncthreads();
  for (int off = 1; off < 256; off <<= 1) {
    int v = 0;
    if (t >= off) v = sb[t - off];
    __syncthreads();
    sb[t] += v;
    __syncthreads();
  }
  int run = sb[t] - s4;
  #pragma unroll
  for (int k = 0; k < 4; ++k) { offs[base + t * 4 + k] = run; run += c[k]; }
  if (t == 255) bsum[blockIdx.x] = sb[255];
}

__global__ __launch_bounds__(256) void scan2_kernel(int* __restrict__ offs, int* __restrict__ cur,
                                                    const int* __restrict__ bsum) {
  __shared__ int baseS;
  int t = threadIdx.x;
  int i = blockIdx.x * 256 + t;
  int chunk = blockIdx.x >> 2;
  if (t == 0) {
    int s = 0;
    for (int j = 0; j < chunk; ++j) s += bsum[j];
    baseS = s;
  }
  __syncthreads();
  int v = offs[i] + baseS;
  offs[i] = v;
  cur[i] = v;
}

__global__ __launch_bounds__(256) void scatter_kernel(const int* __restrict__ eidx,
                                                      int* __restrict__ cur, int* __restrict__ elist) {
  int e = blockIdx.x * 256 + threadIdx.x;
  if (e < N_EDGES) {
    int p = atomicAdd(&cur[eidx[e]], 1);
    elist[p] = e;
  }
}

// ==== edge kernel ====
// CSR mode (medge!=0): block handles CSR positions [64b,64b+64); edge ids via elist;
//   output rows stored CONTIGUOUSLY at medge[p0+r]. hdst gathers are sorted -> L1/L2 reuse.
// Fallback mode: natural edge order + f32 atomics into mi.
__global__ __launch_bounds__(256, 4) void edge_kernel(
    const f16* __restrict__ h16, const int* __restrict__ eidx,
    const float* __restrict__ eattr, const int* __restrict__ elist,
    const f16* __restrict__ Wp, const float* __restrict__ be1,
    const float* __restrict__ be2,
    const float* __restrict__ Wg, const float* __restrict__ bg,
    float* __restrict__ mi, f16* __restrict__ medge) {
  __shared__ f16 X[64 * XS];
  __shared__ float part[64 * 4];
  __shared__ float eijL[64];
  __shared__ int dstL[64];
  int t = threadIdx.x;
  int p0 = blockIdx.x * 64;

  if (!medge && t < 64) dstL[t] = eidx[p0 + t];
  // ---- stage X: h[dst] (cols 0..127), h[src] (cols 128..255) ----
  {
    int rb = t >> 4, ch = t & 15;
    for (int p = 0; p < 4; ++p) {
      int r = p * 16 + rb;
      int e = medge ? elist[p0 + r] : (p0 + r);
      int d = eidx[e];
      int s = eidx[N_EDGES + e];
      *(uint4*)&X[r * XS + ch * 8]       = *(const uint4*)(h16 + (size_t)d * HID + ch * 8);
      *(uint4*)&X[r * XS + 128 + ch * 8] = *(const uint4*)(h16 + (size_t)s * HID + ch * 8);
    }
  }
  // ---- stage edge_attr (cols 256..279) ----
  for (int i = t; i < 384; i += 256) {
    int el = i / 6, ck = i % 6;
    int e = medge ? elist[p0 + el] : (p0 + el);
    float4 f = *(const float4*)(eattr + (size_t)e * 24 + ck * 4);
    half4 hv = {(f16)f.x, (f16)f.y, (f16)f.z, (f16)f.w};
    *(half4*)&X[el * XS + 256 + ck * 4] = hv;
  }
  if (t < 64) { uint4 z = {0, 0, 0, 0}; *(uint4*)&X[t * XS + 280] = z; }
  __syncthreads();

  int w = t >> 6, lane = t & 63, q = lane >> 4, c = lane & 15;
  int colBase = w * 32;
  const f16* Bp1 = Wp + WB1;
  const f16* Bp2 = Wp + WB2;

  // ---- layer 1 ----
  f32x4 acc[4][2];
  {
    float b0 = be1[colBase + c], b1 = be1[colBase + 16 + c];
    #pragma unroll
    for (int mt = 0; mt < 4; ++mt) {
      acc[mt][0] = (f32x4){b0, b0, b0, b0};
      acc[mt][1] = (f32x4){b1, b1, b1, b1};
    }
  }
  const f16* bp1base = Bp1 + ((size_t)(q * 128 + colBase + c)) * 8;
  half8 bf0 = *(const half8*)(bp1base);
  half8 bf1 = *(const half8*)(bp1base + 128);
  #pragma unroll
  for (int ks = 0; ks < 9; ++ks) {
    half8 nb0, nb1;
    if (ks < 8) {
      nb0 = *(const half8*)(bp1base + (ks + 1) * 4096);
      nb1 = *(const half8*)(bp1base + (ks + 1) * 4096 + 128);
    }
    #pragma unroll
    for (int mt = 0; mt < 4; ++mt) {
      half8 a = *(const half8*)&X[(mt * 16 + c) * XS + ks * 32 + q * 8];
      acc[mt][0] = __builtin_amdgcn_mfma_f32_16x16x32_f16(a, bf0, acc[mt][0], 0, 0, 0);
      acc[mt][1] = __builtin_amdgcn_mfma_f32_16x16x32_f16(a, bf1, acc[mt][1], 0, 0, 0);
    }
    bf0 = nb0; bf1 = nb1;
  }

  const f16* bp2base = Bp2 + ((size_t)(q * 128 + colBase + c)) * 8;
  half8 d0 = *(const half8*)(bp2base);
  half8 d1 = *(const half8*)(bp2base + 128);

  __syncthreads();
  f16* T = X;   // alias
  #pragma unroll
  for (int mt = 0; mt < 4; ++mt)
    #pragma unroll
    for (int nt = 0; nt < 2; ++nt)
      #pragma unroll
      for (int r = 0; r < 4; ++r) {
        float v = acc[mt][nt][r];
        T[(mt * 16 + q * 4 + r) * TS + colBase + nt * 16 + c] = (f16)(v > 0.f ? v : 0.f);
      }
  __syncthreads();

  // ---- layer 2 ----
  f32x4 m2[4][2];
  {
    float b0 = be2[colBase + c], b1 = be2[colBase + 16 + c];
    #pragma unroll
    for (int mt = 0; mt < 4; ++mt) {
      m2[mt][0] = (f32x4){b0, b0, b0, b0};
      m2[mt][1] = (f32x4){b1, b1, b1, b1};
    }
  }
  #pragma unroll
  for (int kk = 0; kk < 4; ++kk) {
    half8 n0, n1;
    if (kk < 3) {
      n0 = *(const half8*)(bp2base + (kk + 1) * 4096);
      n1 = *(const half8*)(bp2base + (kk + 1) * 4096 + 128);
    }
    #pragma unroll
    for (int mt = 0; mt < 4; ++mt) {
      half8 a = *(const half8*)&T[(mt * 16 + c) * TS + kk * 32 + q * 8];
      m2[mt][0] = __builtin_amdgcn_mfma_f32_16x16x32_f16(a, d0, m2[mt][0], 0, 0, 0);
      m2[mt][1] = __builtin_amdgcn_mfma_f32_16x16x32_f16(a, d1, m2[mt][1], 0, 0, 0);
    }
    d0 = n0; d1 = n1;
  }

  // ---- relu + gate ----
  float wg0 = Wg[colBase + c], wg1 = Wg[colBase + 16 + c];
  float pd[4][4];
  #pragma unroll
  for (int mt = 0; mt < 4; ++mt)
    #pragma unroll
    for (int r = 0; r < 4; ++r) {
      float v0 = m2[mt][0][r]; v0 = v0 > 0.f ? v0 : 0.f; m2[mt][0][r] = v0;
      float v1 = m2[mt][1][r]; v1 = v1 > 0.f ? v1 : 0.f; m2[mt][1][r] = v1;
      pd[mt][r] = v0 * wg0 + v1 * wg1;
    }
  #pragma unroll
  for (int off = 1; off < 16; off <<= 1)
    #pragma unroll
    for (int mt = 0; mt < 4; ++mt)
      #pragma unroll
      for (int r = 0; r < 4; ++r)
        pd[mt][r] += __shfl_xor(pd[mt][r], off, 64);
  if (c == 0)
    #pragma unroll
    for (int mt = 0; mt < 4; ++mt)
      #pragma unroll
      for (int r = 0; r < 4; ++r)
        part[(mt * 16 + q * 4 + r) * 4 + w] = pd[mt][r];
  __syncthreads();
  if (t < 64) {
    float s = part[t * 4] + part[t * 4 + 1] + part[t * 4 + 2] + part[t * 4 + 3] + bg[0];
    eijL[t] = 1.f / (1.f + __expf(-s));
  }
  __syncthreads();

  if (medge) {
    // gated f16 -> T, then block-contiguous 16KB store at CSR positions
    #pragma unroll
    for (int mt = 0; mt < 4; ++mt)
      #pragma unroll
      for (int r = 0; r < 4; ++r) {
        int el = mt * 16 + q * 4 + r;
        float ev = eijL[el];
        T[el * TS + colBase + c]      = (f16)(m2[mt][0][r] * ev);
        T[el * TS + colBase + 16 + c] = (f16)(m2[mt][1][r] * ev);
      }
    __syncthreads();
    int r = t >> 2, p = t & 3;
    uint4* dst = (uint4*)(medge + (size_t)(p0 + r) * HID + p * 32);
    const uint4* s = (const uint4*)&T[r * TS + p * 32];
    dst[0] = s[0]; dst[1] = s[1]; dst[2] = s[2]; dst[3] = s[3];
  } else {
    #pragma unroll
    for (int mt = 0; mt < 4; ++mt)
      #pragma unroll
      for (int r = 0; r < 4; ++r) {
        int el = mt * 16 + q * 4 + r;
        float ev = eijL[el];
        float* base = mi + (size_t)dstL[el] * HID + colBase + c;
        atomicAdd(base,      m2[mt][0][r] * ev);
        atomicAdd(base + 16, m2[mt][1][r] * ev);
      }
  }
}

// ==== CSR node kernel: medge rows for node g are CONTIGUOUS [offs[g], offs[g]+cnt[g]) ====
__global__ __launch_bounds__(256, 4) void node_kernel_csr(
    const f16* __restrict__ medge,
    const int* __restrict__ offs, const int* __restrict__ cnt,
    const f16* __restrict__ h16,
    const f16* __restrict__ Wp, const float* __restrict__ bn1,
    const float* __restrict__ bn2, float* __restrict__ out) {
  __shared__ f16 Y[64 * YS];
  int t = threadIdx.x;
  int n0 = blockIdx.x * 64;
  {
    int r = t >> 2, p = t & 3;
    int g = n0 + r;
    int start = 0, deg = 0;
    if (g < N_NODES) { start = offs[g]; deg = cnt[g]; } else g = N_NODES - 1;
    const f16* mrow = medge + (size_t)start * HID + p * 32;
    float a0[8] = {0,0,0,0,0,0,0,0}, a1[8] = {0,0,0,0,0,0,0,0};
    float a2[8] = {0,0,0,0,0,0,0,0}, a3[8] = {0,0,0,0,0,0,0,0};
    #pragma unroll 2
    for (int i = 0; i < deg; ++i) {
      const half8* mp = (const half8*)(mrow + (size_t)i * HID);
      half8 v0 = mp[0], v1 = mp[1], v2 = mp[2], v3 = mp[3];
      #pragma unroll
      for (int j = 0; j < 8; ++j) {
        a0[j] += (float)v0[j]; a1[j] += (float)v1[j];
        a2[j] += (float)v2[j]; a3[j] += (float)v3[j];
      }
    }
    half8 o0, o1, o2, o3;
    #pragma unroll
    for (int j = 0; j < 8; ++j) {
      o0[j] = (f16)a0[j]; o1[j] = (f16)a1[j]; o2[j] = (f16)a2[j]; o3[j] = (f16)a3[j];
    }
    half8* yr = (half8*)&Y[r * YS + p * 32];
    yr[0] = o0; yr[1] = o1; yr[2] = o2; yr[3] = o3;
    const uint4* hs = (const uint4*)(h16 + (size_t)g * HID + p * 32);
    uint4* yh = (uint4*)&Y[r * YS + 128 + p * 32];
    yh[0] = hs[0]; yh[1] = hs[1]; yh[2] = hs[2]; yh[3] = hs[3];
  }
  __syncthreads();

  int w = t >> 6, lane = t & 63, q = lane >> 4, c = lane & 15;
  int colBase = w * 32;
  const f16* BN1 = Wp + WN1;
  const f16* BN2 = Wp + WN2;

  f32x4 acc[4][2];
  {
    float b0 = bn1[colBase + c], b1 = bn1[colBase + 16 + c];
    #pragma unroll
    for (int mt = 0; mt < 4; ++mt) {
      acc[mt][0] = (f32x4){b0, b0, b0, b0};
      acc[mt][1] = (f32x4){b1, b1, b1, b1};
    }
  }
  const f16* bn1base = BN1 + ((size_t)(q * 128 + colBase + c)) * 8;
  half8 bf0 = *(const half8*)(bn1base);
  half8 bf1 = *(const half8*)(bn1base + 128);
  #pragma unroll
  for (int ks = 0; ks < 8; ++ks) {
    half8 nb0, nb1;
    if (ks < 7) {
      nb0 = *(const half8*)(bn1base + (ks + 1) * 4096);
      nb1 = *(const half8*)(bn1base + (ks + 1) * 4096 + 128);
    }
    #pragma unroll
    for (int mt = 0; mt < 4; ++mt) {
      half8 a = *(const half8*)&Y[(mt * 16 + c) * YS + ks * 32 + q * 8];
      acc[mt][0] = __builtin_amdgcn_mfma_f32_16x16x32_f16(a, bf0, acc[mt][0], 0, 0, 0);
      acc[mt][1] = __builtin_amdgcn_mfma_f32_16x16x32_f16(a, bf1, acc[mt][1], 0, 0, 0);
    }
    bf0 = nb0; bf1 = nb1;
  }
  const f16* bn2base = BN2 + ((size_t)(q * 128 + colBase + c)) * 8;
  half8 d0 = *(const half8*)(bn2base);
  half8 d1 = *(const half8*)(bn2base + 128);

  __syncthreads();
  f16* T = Y;
  #pragma unroll
  for (int mt = 0; mt < 4; ++mt)
    #pragma unroll
    for (int nt = 0; nt < 2; ++nt)
      #pragma unroll
      for (int r = 0; r < 4; ++r) {
        float v = acc[mt][nt][r];
        T[(mt * 16 + q * 4 + r) * TS + colBase + nt * 16 + c] = (f16)(v > 0.f ? v : 0.f);
      }
  __syncthreads();

  f32x4 m2[4][2];
  {
    float b0 = bn2[colBase + c], b1 = bn2[colBase + 16 + c];
    #pragma unroll
    for (int mt = 0; mt < 4; ++mt) {
      m2[mt][0] = (f32x4){b0, b0, b0, b0};
      m2[mt][1] = (f32x4){b1, b1, b1, b1};
    }
  }
  #pragma unroll
  for (int kk = 0; kk < 4; ++kk) {
    half8 n0, n1;
    if (kk < 3) {
      n0 = *(const half8*)(bn2base + (kk + 1) * 4096);
      n1 = *(const half8*)(bn2base + (kk + 1) * 4096 + 128);
    }
    #pragma unroll
    for (int mt = 0; mt < 4; ++mt) {
      half8 a = *(const half8*)&T[(mt * 16 + c) * TS + kk * 32 + q * 8];
      m2[mt][0] = __builtin_amdgcn_mfma_f32_16x16x32_f16(a, d0, m2[mt][0], 0, 0, 0);
      m2[mt][1] = __builtin_amdgcn_mfma_f32_16x16x32_f16(a, d1, m2[mt][1], 0, 0, 0);
    }
    d0 = n0; d1 = n1;
  }
  #pragma unroll
  for (int mt = 0; mt < 4; ++mt)
    #pragma unroll
    for (int r = 0; r < 4; ++r) {
      int g = n0 + mt * 16 + q * 4 + r;
      if (g < N_NODES) {
        float* o = out + (size_t)g * HID + colBase + c;
        o[0]  = m2[mt][0][r];
        o[16] = m2[mt][1][r];
      }
    }
}

// ==== fallback node kernel (reads f32 mi) ====
__global__ __launch_bounds__(256, 4) void node_kernel(
    const float* __restrict__ mi, const f16* __restrict__ h16,
    const f16* __restrict__ Wp, const float* __restrict__ bn1,
    const float* __restrict__ bn2, float* __restrict__ out) {
  __shared__ f16 Y[64 * YS];
  int t = threadIdx.x;
  int n0 = blockIdx.x * 64;
  {
    int rb = t >> 4, ch = t & 15;
    for (int p = 0; p < 4; ++p) {
      int r = p * 16 + rb;
      int g = n0 + r; if (g >= N_NODES) g = N_NODES - 1;
      const float4* s = (const float4*)(mi + (size_t)g * HID + ch * 8);
      float4 a = s[0], b = s[1];
      half8 v = {(f16)a.x, (f16)a.y, (f16)a.z, (f16)a.w,
                 (f16)b.x, (f16)b.y, (f16)b.z, (f16)b.w};
      *(half8*)&Y[r * YS + ch * 8] = v;
      *(uint4*)&Y[r * YS + 128 + ch * 8] = *(const uint4*)(h16 + (size_t)g * HID + ch * 8);
    }
  }
  __syncthreads();
  int w = t >> 6, lane = t & 63, q = lane >> 4, c = lane & 15;
  int colBase = w * 32;
  const f16* BN1 = Wp + WN1;
  const f16* BN2 = Wp + WN2;
  f32x4 acc[4][2];
  {
    float b0 = bn1[colBase + c], b1 = bn1[colBase + 16 + c];
    #pragma unroll
    for (int mt = 0; mt < 4; ++mt) {
      acc[mt][0] = (f32x4){b0, b0, b0, b0};
      acc[mt][1] = (f32x4){b1, b1, b1, b1};
    }
  }
  const f16* bn1base = BN1 + ((size_t)(q * 128 + colBase + c)) * 8;
  half8 bf0 = *(const half8*)(bn1base);
  half8 bf1 = *(const half8*)(bn1base + 128);
  #pragma unroll
  for (int ks = 0; ks < 8; ++ks) {
    half8 nb0, nb1;
    if (ks < 7) {
      nb0 = *(const half8*)(bn1base + (ks + 1) * 4096);
      nb1 = *(const half8*)(bn1base + (ks + 1) * 4096 + 128);
    }
    #pragma unroll
    for (int mt = 0; mt < 4; ++mt) {
      half8 a = *(const half8*)&Y[(mt * 16 + c) * YS + ks * 32 + q * 8];
      acc[mt][0] = __builtin_amdgcn_mfma_f32_16x16x32_f16(a, bf0, acc[mt][0], 0, 0, 0);
      acc[mt][1] = __builtin_amdgcn_mfma_f32_16x16x32_f16(a, bf1, acc[mt][1], 0, 0, 0);
    }
    bf0 = nb0; bf1 = nb1;
  }
  const f16* bn2base = BN2 + ((size_t)(q * 128 + colBase + c)) * 8;
  half8 d0 = *(const half8*)(bn2base);
  half8 d1 = *(const half8*)(bn2base + 128);
  __syncthreads();
  f16* T = Y;
  #pragma unroll
  for (int mt = 0; mt < 4; ++mt)
    #pragma unroll
    for (int nt = 0; nt < 2; ++nt)
      #pragma unroll
      for (int r = 0; r < 4; ++r) {
        float v = acc[mt][nt][r];
        T[(mt * 16 + q * 4 + r) * TS + colBase + nt * 16 + c] = (f16)(v > 0.f ? v : 0.f);
      }
  __syncthreads();
  f32x4 m2[4][2];
  {
    float b0 = bn2[colBase + c], b1 = bn2[colBase + 16 + c];
    #pragma unroll
    for (int mt = 0; mt < 4; ++mt) {
      m2[mt][0] = (f32x4){b0, b0, b0, b0};
      m2[mt][1] = (f32x4){b1, b1, b1, b1};
    }
  }
  #pragma unroll
  for (int kk = 0; kk < 4; ++kk) {
    half8 n0, n1;
    if (kk < 3) {
      n0 = *(const half8*)(bn2base + (kk + 1) * 4096);
      n1 = *(const half8*)(bn2base + (kk + 1) * 4096 + 128);
    }
    #pragma unroll
    for (int mt = 0; mt < 4; ++mt) {
      half8 a = *(const half8*)&T[(mt * 16 + c) * TS + kk * 32 + q * 8];
      m2[mt][0] = __builtin_amdgcn_mfma_f32_16x16x32_f16(a, d0, m2[mt][0], 0, 0, 0);
      m2[mt][1] = __builtin_amdgcn_mfma_f32_16x16x32_f16(a, d1, m2[mt][1], 0, 0, 0);
    }
    d0 = n0; d1 = n1;
  }
  #pragma unroll
  for (int mt = 0; mt < 4; ++mt)
    #pragma unroll
    for (int r = 0; r < 4; ++r) {
      int g = n0 + mt * 16 + q * 4 + r;
      if (g < N_NODES) {
        float* o = out + (size_t)g * HID + colBase + c;
        o[0]  = m2[mt][0][r];
        o[16] = m2[mt][1][r];
      }
    }
}

extern "C" void kernel_launch(void* const* d_in, const int* in_sizes, int n_in,
                              void* d_out, int out_size, void* d_ws, size_t ws_size,
                              hipStream_t stream) {
  const float* h    = (const float*)d_in[0];
  const int*   eidx = (const int*)d_in[1];
  const float* eattr= (const float*)d_in[2];
  const float* We1  = (const float*)d_in[3];
  const float* be1  = (const float*)d_in[4];
  const float* We2  = (const float*)d_in[5];
  const float* be2  = (const float*)d_in[6];
  const float* Wg   = (const float*)d_in[7];
  const float* bg   = (const float*)d_in[8];
  const float* Wn1  = (const float*)d_in[9];
  const float* bn1  = (const float*)d_in[10];
  const float* Wn2  = (const float*)d_in[11];
  const float* bn2  = (const float*)d_in[12];
  float* out = (float*)d_out;
  char* ws = (char*)d_ws;

  if (ws_size >= CSR_TOTAL) {
    f16* medge = (f16*)(ws + OFF_MEDGE);
    f16* h16   = (f16*)(ws + OFF_H16C);
    f16* Wp    = (f16*)(ws + OFF_WC);
    int* cnt   = (int*)(ws + OFF_CNT);
    int* offs  = (int*)(ws + OFF_OFFS);
    int* cur   = (int*)(ws + OFF_CUR);
    int* bsum  = (int*)(ws + OFF_BSUM);
    int* elist = (int*)(ws + OFF_ELIST);

    hipMemsetAsync(cnt, 0, 50176 * sizeof(int), stream);
    pack_weights<<<400, 256, 0, stream>>>(We1, We2, Wn1, Wn2, Wp);
    convert_h<<<3125, 256, 0, stream>>>(h, h16);
    hist_kernel<<<3125, 256, 0, stream>>>(eidx, cnt);
    scan1_kernel<<<49, 256, 0, stream>>>(cnt, offs, bsum);
    scan2_kernel<<<196, 256, 0, stream>>>(offs, cur, bsum);
    scatter_kernel<<<3125, 256, 0, stream>>>(eidx, cur, elist);
    edge_kernel<<<N_EDGES / 64, 256, 0, stream>>>(h16, eidx, eattr, elist, Wp, be1, be2,
                                                  Wg, bg, nullptr, medge);
    node_kernel_csr<<<(N_NODES + 63) / 64, 256, 0, stream>>>(medge, offs, cnt, h16,
                                                             Wp, bn1, bn2, out);
  } else {
    float* mi  = (float*)(ws + OFF_MI);
    f16*   h16 = (f16*)(ws + OFF_H16);
    f16*   Wp  = (f16*)(ws + OFF_W);

    hipMemsetAsync(mi, 0, (size_t)N_NODES * HID * sizeof(float), stream);
    pack_weights<<<400, 256, 0, stream>>>(We1, We2, Wn1, Wn2, Wp);
    convert_h<<<3125, 256, 0, stream>>>(h, h16);
    edge_kernel<<<N_EDGES / 64, 256, 0, stream>>>(h16, eidx, eattr, nullptr, Wp, be1, be2,
                                                  Wg, bg, mi, nullptr);
    node_kernel<<<(N_NODES + 63) / 64, 256, 0, stream>>>(mi, h16, Wp, bn1, bn2, out);
  }
}

// Round 5
// 509.661 us; speedup vs baseline: 1.0205x; 1.0205x over previous
//
#include <hip/hip_runtime.h>

#define N_NODES 50000
#define N_EDGES 800000
#define HID 128

typedef _Float16 f16;
typedef _Float16 half8 __attribute__((ext_vector_type(8)));
typedef _Float16 half4 __attribute__((ext_vector_type(4)));
typedef float f32x4 __attribute__((ext_vector_type(4)));

// ---- CSR-path workspace layout (bytes) ----
#define OFF_MEDGE  0UL             // 800000*128*2 = 204,800,000  (CSR-ordered gated messages)
#define OFF_H16C   204800000UL     // 12,800,000
#define OFF_WC     217600000UL     // packed weights: 204,800
#define OFF_CNT    217804800UL     // 50176*4 = 200,704
#define OFF_OFFS   218005504UL     // 200,704
#define OFF_CUR    218206208UL     // 200,704
#define OFF_BSUM   218406912UL     // 1,024 (unused now, kept for layout stability)
#define OFF_POS    218407936UL     // 3,200,000  (pos[e] = CSR slot of edge e)
#define CSR_TOTAL  221607936UL

// ---- fallback (atomic-path) layout ----
#define OFF_MI   0UL
#define OFF_H16  25600000UL
#define OFF_W    38400000UL

#define WB1 0
#define WB2 36864
#define WN1 53248
#define WN2 86016

#define XS 296   // X tile stride (f16): 128 hdst | 128 hsrc | 24 attr | 8 zero | 8 unused
#define TS 136   // T tile stride (aliased into X buffer)
#define YS 264   // node Y tile stride (256 + pad)

// pack weights into B-fragment layout; also zero cnt (CSR path) to save a memset dispatch
__global__ __launch_bounds__(256) void pack_weights(
    const float* __restrict__ We1, const float* __restrict__ We2,
    const float* __restrict__ Wn1, const float* __restrict__ Wn2,
    f16* __restrict__ W, int* __restrict__ cnt) {
  int i = blockIdx.x * 256 + threadIdx.x;   // 0..102399
  if (cnt && i < 50176) cnt[i] = 0;
  if (i < 36864) {                          // We1 (rows permuted: h first, attr last)
    int j = i & 7, n = (i >> 3) & 127, qk = i >> 10;
    int k = qk * 8 + j;
    float v = 0.f;
    if (k < 256) v = We1[(24 + k) * 128 + n];
    else if (k < 280) v = We1[(k - 256) * 128 + n];
    W[WB1 + i] = (f16)v;
  } else if (i < 53248) {                   // We2
    int l = i - 36864;
    int j = l & 7, n = (l >> 3) & 127, qk = l >> 10;
    W[WB2 + l] = (f16)We2[(qk * 8 + j) * 128 + n];
  } else if (i < 86016) {                   // Wn1
    int l = i - 53248;
    int j = l & 7, n = (l >> 3) & 127, qk = l >> 10;
    W[WN1 + l] = (f16)Wn1[(qk * 8 + j) * 128 + n];
  } else if (i < 102400) {                  // Wn2
    int l = i - 86016;
    int j = l & 7, n = (l >> 3) & 127, qk = l >> 10;
    W[WN2 + l] = (f16)Wn2[(qk * 8 + j) * 128 + n];
  }
}

// h f32 -> f16 (800K threads); fused degree histogram (CSR path)
__global__ __launch_bounds__(256) void convert_hist(
    const float* __restrict__ h, const int* __restrict__ eidx,
    f16* __restrict__ h16, int* __restrict__ cnt) {
  int i = blockIdx.x * 256 + threadIdx.x;   // 0..799999 exactly
  const float4* src = (const float4*)h + (size_t)i * 2;
  float4 a = src[0], b = src[1];
  half8 v = {(f16)a.x, (f16)a.y, (f16)a.z, (f16)a.w,
             (f16)b.x, (f16)b.y, (f16)b.z, (f16)b.w};
  *((half8*)h16 + i) = v;
  if (cnt) atomicAdd(&cnt[eidx[i]], 1);
}

// single-block exclusive scan of 50176 counts -> offs, cur
__global__ __launch_bounds__(256) void scan_kernel(const int* __restrict__ cnt,
                                                   int* __restrict__ offs, int* __restrict__ cur) {
  __shared__ int sb[256];
  int t = threadIdx.x;
  int base = t * 196;               // 256*196 = 50176
  int s = 0;
  for (int k = 0; k < 196; ++k) s += cnt[base + k];
  sb[t] = s;
  __syncthreads();
  for (int off = 1; off < 256; off <<= 1) {
    int v = (t >= off) ? sb[t - off] : 0;
    __syncthreads();
    sb[t] += v;
    __syncthreads();
  }
  int run = sb[t] - s;              // exclusive base of this thread's segment
  for (int k = 0; k < 196; ++k) {
    int c = cnt[base + k];
    offs[base + k] = run;
    cur[base + k] = run;
    run += c;
  }
}

// pos[e] = CSR slot for edge e (inverse permutation)
__global__ __launch_bounds__(256) void scatter_kernel(const int* __restrict__ eidx,
                                                      int* __restrict__ cur, int* __restrict__ pos) {
  int e = blockIdx.x * 256 + threadIdx.x;
  if (e < N_EDGES) pos[e] = atomicAdd(&cur[eidx[e]], 1);
}

// ==== edge kernel: NATURAL-order staging (coalesced eidx/eattr); CSR mode scatter-stores
//      each finished 256B row to medge[pos[e]] so the node kernel reads contiguously ====
__global__ __launch_bounds__(256, 4) void edge_kernel(
    const f16* __restrict__ h16, const int* __restrict__ eidx,
    const float* __restrict__ eattr, const int* __restrict__ pos,
    const f16* __restrict__ Wp, const float* __restrict__ be1,
    const float* __restrict__ be2,
    const float* __restrict__ Wg, const float* __restrict__ bg,
    float* __restrict__ mi, f16* __restrict__ medge) {
  __shared__ f16 X[64 * XS];
  __shared__ float part[64 * 4];
  __shared__ float eijL[64];
  __shared__ int idxL[64];   // CSR: pos[e]; fallback: dst[e]
  int t = threadIdx.x;
  int e0 = blockIdx.x * 64;

  if (t < 64) idxL[t] = medge ? pos[e0 + t] : eidx[e0 + t];
  // ---- stage X: h[dst] (cols 0..127), h[src] (cols 128..255) ----
  {
    int rb = t >> 4, ch = t & 15;
    for (int p = 0; p < 4; ++p) {
      int r = p * 16 + rb;
      int d = eidx[e0 + r];
      int s = eidx[N_EDGES + e0 + r];
      *(uint4*)&X[r * XS + ch * 8]       = *(const uint4*)(h16 + (size_t)d * HID + ch * 8);
      *(uint4*)&X[r * XS + 128 + ch * 8] = *(const uint4*)(h16 + (size_t)s * HID + ch * 8);
    }
  }
  // ---- stage edge_attr (cols 256..279), fully coalesced ----
  for (int i = t; i < 384; i += 256) {
    int el = i / 6, kk = (i % 6) * 4;
    float4 f = *(const float4*)(eattr + (size_t)e0 * 24 + (size_t)i * 4);
    half4 hv = {(f16)f.x, (f16)f.y, (f16)f.z, (f16)f.w};
    *(half4*)&X[el * XS + 256 + kk] = hv;
  }
  if (t < 64) { uint4 z = {0, 0, 0, 0}; *(uint4*)&X[t * XS + 280] = z; }
  __syncthreads();

  int w = t >> 6, lane = t & 63, q = lane >> 4, c = lane & 15;
  int colBase = w * 32;
  const f16* Bp1 = Wp + WB1;
  const f16* Bp2 = Wp + WB2;

  // ---- layer 1 ----
  f32x4 acc[4][2];
  {
    float b0 = be1[colBase + c], b1 = be1[colBase + 16 + c];
    #pragma unroll
    for (int mt = 0; mt < 4; ++mt) {
      acc[mt][0] = (f32x4){b0, b0, b0, b0};
      acc[mt][1] = (f32x4){b1, b1, b1, b1};
    }
  }
  const f16* bp1base = Bp1 + ((size_t)(q * 128 + colBase + c)) * 8;
  half8 bf0 = *(const half8*)(bp1base);
  half8 bf1 = *(const half8*)(bp1base + 128);
  #pragma unroll
  for (int ks = 0; ks < 9; ++ks) {
    half8 nb0, nb1;
    if (ks < 8) {
      nb0 = *(const half8*)(bp1base + (ks + 1) * 4096);
      nb1 = *(const half8*)(bp1base + (ks + 1) * 4096 + 128);
    }
    #pragma unroll
    for (int mt = 0; mt < 4; ++mt) {
      half8 a = *(const half8*)&X[(mt * 16 + c) * XS + ks * 32 + q * 8];
      acc[mt][0] = __builtin_amdgcn_mfma_f32_16x16x32_f16(a, bf0, acc[mt][0], 0, 0, 0);
      acc[mt][1] = __builtin_amdgcn_mfma_f32_16x16x32_f16(a, bf1, acc[mt][1], 0, 0, 0);
    }
    bf0 = nb0; bf1 = nb1;
  }

  const f16* bp2base = Bp2 + ((size_t)(q * 128 + colBase + c)) * 8;
  half8 d0 = *(const half8*)(bp2base);
  half8 d1 = *(const half8*)(bp2base + 128);

  __syncthreads();
  f16* T = X;   // alias
  #pragma unroll
  for (int mt = 0; mt < 4; ++mt)
    #pragma unroll
    for (int nt = 0; nt < 2; ++nt)
      #pragma unroll
      for (int r = 0; r < 4; ++r) {
        float v = acc[mt][nt][r];
        T[(mt * 16 + q * 4 + r) * TS + colBase + nt * 16 + c] = (f16)(v > 0.f ? v : 0.f);
      }
  __syncthreads();

  // ---- layer 2 ----
  f32x4 m2[4][2];
  {
    float b0 = be2[colBase + c], b1 = be2[colBase + 16 + c];
    #pragma unroll
    for (int mt = 0; mt < 4; ++mt) {
      m2[mt][0] = (f32x4){b0, b0, b0, b0};
      m2[mt][1] = (f32x4){b1, b1, b1, b1};
    }
  }
  #pragma unroll
  for (int kk = 0; kk < 4; ++kk) {
    half8 n0, n1;
    if (kk < 3) {
      n0 = *(const half8*)(bp2base + (kk + 1) * 4096);
      n1 = *(const half8*)(bp2base + (kk + 1) * 4096 + 128);
    }
    #pragma unroll
    for (int mt = 0; mt < 4; ++mt) {
      half8 a = *(const half8*)&T[(mt * 16 + c) * TS + kk * 32 + q * 8];
      m2[mt][0] = __builtin_amdgcn_mfma_f32_16x16x32_f16(a, d0, m2[mt][0], 0, 0, 0);
      m2[mt][1] = __builtin_amdgcn_mfma_f32_16x16x32_f16(a, d1, m2[mt][1], 0, 0, 0);
    }
    d0 = n0; d1 = n1;
  }

  // ---- relu + gate ----
  float wg0 = Wg[colBase + c], wg1 = Wg[colBase + 16 + c];
  float pd[4][4];
  #pragma unroll
  for (int mt = 0; mt < 4; ++mt)
    #pragma unroll
    for (int r = 0; r < 4; ++r) {
      float v0 = m2[mt][0][r]; v0 = v0 > 0.f ? v0 : 0.f; m2[mt][0][r] = v0;
      float v1 = m2[mt][1][r]; v1 = v1 > 0.f ? v1 : 0.f; m2[mt][1][r] = v1;
      pd[mt][r] = v0 * wg0 + v1 * wg1;
    }
  #pragma unroll
  for (int off = 1; off < 16; off <<= 1)
    #pragma unroll
    for (int mt = 0; mt < 4; ++mt)
      #pragma unroll
      for (int r = 0; r < 4; ++r)
        pd[mt][r] += __shfl_xor(pd[mt][r], off, 64);
  if (c == 0)
    #pragma unroll
    for (int mt = 0; mt < 4; ++mt)
      #pragma unroll
      for (int r = 0; r < 4; ++r)
        part[(mt * 16 + q * 4 + r) * 4 + w] = pd[mt][r];
  __syncthreads();
  if (t < 64) {
    float s = part[t * 4] + part[t * 4 + 1] + part[t * 4 + 2] + part[t * 4 + 3] + bg[0];
    eijL[t] = 1.f / (1.f + __expf(-s));
  }
  __syncthreads();

  if (medge) {
    // gated f16 -> T, then per-row scatter store to CSR slot (256B row = full lines)
    #pragma unroll
    for (int mt = 0; mt < 4; ++mt)
      #pragma unroll
      for (int r = 0; r < 4; ++r) {
        int el = mt * 16 + q * 4 + r;
        float ev = eijL[el];
        T[el * TS + colBase + c]      = (f16)(m2[mt][0][r] * ev);
        T[el * TS + colBase + 16 + c] = (f16)(m2[mt][1][r] * ev);
      }
    __syncthreads();
    int r = t >> 2, p = t & 3;
    uint4* dst = (uint4*)(medge + (size_t)idxL[r] * HID + p * 32);
    const uint4* s = (const uint4*)&T[r * TS + p * 32];
    dst[0] = s[0]; dst[1] = s[1]; dst[2] = s[2]; dst[3] = s[3];
  } else {
    #pragma unroll
    for (int mt = 0; mt < 4; ++mt)
      #pragma unroll
      for (int r = 0; r < 4; ++r) {
        int el = mt * 16 + q * 4 + r;
        float ev = eijL[el];
        float* base = mi + (size_t)idxL[el] * HID + colBase + c;
        atomicAdd(base,      m2[mt][0][r] * ev);
        atomicAdd(base + 16, m2[mt][1][r] * ev);
      }
  }
}

// ==== CSR node kernel: rows for node g are CONTIGUOUS [offs[g], offs[g]+cnt[g]) ====
__global__ __launch_bounds__(256, 4) void node_kernel_csr(
    const f16* __restrict__ medge,
    const int* __restrict__ offs, const int* __restrict__ cnt,
    const f16* __restrict__ h16,
    const f16* __restrict__ Wp, const float* __restrict__ bn1,
    const float* __restrict__ bn2, float* __restrict__ out) {
  __shared__ f16 Y[64 * YS];
  int t = threadIdx.x;
  int n0 = blockIdx.x * 64;
  {
    int r = t >> 2, p = t & 3;
    int g = n0 + r;
    int start = 0, deg = 0;
    if (g < N_NODES) { start = offs[g]; deg = cnt[g]; } else g = N_NODES - 1;
    const f16* mrow = medge + (size_t)start * HID + p * 32;
    float a0[8] = {0,0,0,0,0,0,0,0}, a1[8] = {0,0,0,0,0,0,0,0};
    float a2[8] = {0,0,0,0,0,0,0,0}, a3[8] = {0,0,0,0,0,0,0,0};
    #pragma unroll 2
    for (int i = 0; i < deg; ++i) {
      const half8* mp = (const half8*)(mrow + (size_t)i * HID);
      half8 v0 = mp[0], v1 = mp[1], v2 = mp[2], v3 = mp[3];
      #pragma unroll
      for (int j = 0; j < 8; ++j) {
        a0[j] += (float)v0[j]; a1[j] += (float)v1[j];
        a2[j] += (float)v2[j]; a3[j] += (float)v3[j];
      }
    }
    half8 o0, o1, o2, o3;
    #pragma unroll
    for (int j = 0; j < 8; ++j) {
      o0[j] = (f16)a0[j]; o1[j] = (f16)a1[j]; o2[j] = (f16)a2[j]; o3[j] = (f16)a3[j];
    }
    half8* yr = (half8*)&Y[r * YS + p * 32];
    yr[0] = o0; yr[1] = o1; yr[2] = o2; yr[3] = o3;
    const uint4* hs = (const uint4*)(h16 + (size_t)g * HID + p * 32);
    uint4* yh = (uint4*)&Y[r * YS + 128 + p * 32];
    yh[0] = hs[0]; yh[1] = hs[1]; yh[2] = hs[2]; yh[3] = hs[3];
  }
  __syncthreads();

  int w = t >> 6, lane = t & 63, q = lane >> 4, c = lane & 15;
  int colBase = w * 32;
  const f16* BN1 = Wp + WN1;
  const f16* BN2 = Wp + WN2;

  f32x4 acc[4][2];
  {
    float b0 = bn1[colBase + c], b1 = bn1[colBase + 16 + c];
    #pragma unroll
    for (int mt = 0; mt < 4; ++mt) {
      acc[mt][0] = (f32x4){b0, b0, b0, b0};
      acc[mt][1] = (f32x4){b1, b1, b1, b1};
    }
  }
  const f16* bn1base = BN1 + ((size_t)(q * 128 + colBase + c)) * 8;
  half8 bf0 = *(const half8*)(bn1base);
  half8 bf1 = *(const half8*)(bn1base + 128);
  #pragma unroll
  for (int ks = 0; ks < 8; ++ks) {
    half8 nb0, nb1;
    if (ks < 7) {
      nb0 = *(const half8*)(bn1base + (ks + 1) * 4096);
      nb1 = *(const half8*)(bn1base + (ks + 1) * 4096 + 128);
    }
    #pragma unroll
    for (int mt = 0; mt < 4; ++mt) {
      half8 a = *(const half8*)&Y[(mt * 16 + c) * YS + ks * 32 + q * 8];
      acc[mt][0] = __builtin_amdgcn_mfma_f32_16x16x32_f16(a, bf0, acc[mt][0], 0, 0, 0);
      acc[mt][1] = __builtin_amdgcn_mfma_f32_16x16x32_f16(a, bf1, acc[mt][1], 0, 0, 0);
    }
    bf0 = nb0; bf1 = nb1;
  }
  const f16* bn2base = BN2 + ((size_t)(q * 128 + colBase + c)) * 8;
  half8 d0 = *(const half8*)(bn2base);
  half8 d1 = *(const half8*)(bn2base + 128);

  __syncthreads();
  f16* T = Y;
  #pragma unroll
  for (int mt = 0; mt < 4; ++mt)
    #pragma unroll
    for (int nt = 0; nt < 2; ++nt)
      #pragma unroll
      for (int r = 0; r < 4; ++r) {
        float v = acc[mt][nt][r];
        T[(mt * 16 + q * 4 + r) * TS + colBase + nt * 16 + c] = (f16)(v > 0.f ? v : 0.f);
      }
  __syncthreads();

  f32x4 m2[4][2];
  {
    float b0 = bn2[colBase + c], b1 = bn2[colBase + 16 + c];
    #pragma unroll
    for (int mt = 0; mt < 4; ++mt) {
      m2[mt][0] = (f32x4){b0, b0, b0, b0};
      m2[mt][1] = (f32x4){b1, b1, b1, b1};
    }
  }
  #pragma unroll
  for (int kk = 0; kk < 4; ++kk) {
    half8 n0, n1;
    if (kk < 3) {
      n0 = *(const half8*)(bn2base + (kk + 1) * 4096);
      n1 = *(const half8*)(bn2base + (kk + 1) * 4096 + 128);
    }
    #pragma unroll
    for (int mt = 0; mt < 4; ++mt) {
      half8 a = *(const half8*)&T[(mt * 16 + c) * TS + kk * 32 + q * 8];
      m2[mt][0] = __builtin_amdgcn_mfma_f32_16x16x32_f16(a, d0, m2[mt][0], 0, 0, 0);
      m2[mt][1] = __builtin_amdgcn_mfma_f32_16x16x32_f16(a, d1, m2[mt][1], 0, 0, 0);
    }
    d0 = n0; d1 = n1;
  }
  #pragma unroll
  for (int mt = 0; mt < 4; ++mt)
    #pragma unroll
    for (int r = 0; r < 4; ++r) {
      int g = n0 + mt * 16 + q * 4 + r;
      if (g < N_NODES) {
        float* o = out + (size_t)g * HID + colBase + c;
        o[0]  = m2[mt][0][r];
        o[16] = m2[mt][1][r];
      }
    }
}

// ==== fallback node kernel (reads f32 mi) ====
__global__ __launch_bounds__(256, 4) void node_kernel(
    const float* __restrict__ mi, const f16* __restrict__ h16,
    const f16* __restrict__ Wp, const float* __restrict__ bn1,
    const float* __restrict__ bn2, float* __restrict__ out) {
  __shared__ f16 Y[64 * YS];
  int t = threadIdx.x;
  int n0 = blockIdx.x * 64;
  {
    int rb = t >> 4, ch = t & 15;
    for (int p = 0; p < 4; ++p) {
      int r = p * 16 + rb;
      int g = n0 + r; if (g >= N_NODES) g = N_NODES - 1;
      const float4* s = (const float4*)(mi + (size_t)g * HID + ch * 8);
      float4 a = s[0], b = s[1];
      half8 v = {(f16)a.x, (f16)a.y, (f16)a.z, (f16)a.w,
                 (f16)b.x, (f16)b.y, (f16)b.z, (f16)b.w};
      *(half8*)&Y[r * YS + ch * 8] = v;
      *(uint4*)&Y[r * YS + 128 + ch * 8] = *(const uint4*)(h16 + (size_t)g * HID + ch * 8);
    }
  }
  __syncthreads();
  int w = t >> 6, lane = t & 63, q = lane >> 4, c = lane & 15;
  int colBase = w * 32;
  const f16* BN1 = Wp + WN1;
  const f16* BN2 = Wp + WN2;
  f32x4 acc[4][2];
  {
    float b0 = bn1[colBase + c], b1 = bn1[colBase + 16 + c];
    #pragma unroll
    for (int mt = 0; mt < 4; ++mt) {
      acc[mt][0] = (f32x4){b0, b0, b0, b0};
      acc[mt][1] = (f32x4){b1, b1, b1, b1};
    }
  }
  const f16* bn1base = BN1 + ((size_t)(q * 128 + colBase + c)) * 8;
  half8 bf0 = *(const half8*)(bn1base);
  half8 bf1 = *(const half8*)(bn1base + 128);
  #pragma unroll
  for (int ks = 0; ks < 8; ++ks) {
    half8 nb0, nb1;
    if (ks < 7) {
      nb0 = *(const half8*)(bn1base + (ks + 1) * 4096);
      nb1 = *(const half8*)(bn1base + (ks + 1) * 4096 + 128);
    }
    #pragma unroll
    for (int mt = 0; mt < 4; ++mt) {
      half8 a = *(const half8*)&Y[(mt * 16 + c) * YS + ks * 32 + q * 8];
      acc[mt][0] = __builtin_amdgcn_mfma_f32_16x16x32_f16(a, bf0, acc[mt][0], 0, 0, 0);
      acc[mt][1] = __builtin_amdgcn_mfma_f32_16x16x32_f16(a, bf1, acc[mt][1], 0, 0, 0);
    }
    bf0 = nb0; bf1 = nb1;
  }
  const f16* bn2base = BN2 + ((size_t)(q * 128 + colBase + c)) * 8;
  half8 d0 = *(const half8*)(bn2base);
  half8 d1 = *(const half8*)(bn2base + 128);
  __syncthreads();
  f16* T = Y;
  #pragma unroll
  for (int mt = 0; mt < 4; ++mt)
    #pragma unroll
    for (int nt = 0; nt < 2; ++nt)
      #pragma unroll
      for (int r = 0; r < 4; ++r) {
        float v = acc[mt][nt][r];
        T[(mt * 16 + q * 4 + r) * TS + colBase + nt * 16 + c] = (f16)(v > 0.f ? v : 0.f);
      }
  __syncthreads();
  f32x4 m2[4][2];
  {
    float b0 = bn2[colBase + c], b1 = bn2[colBase + 16 + c];
    #pragma unroll
    for (int mt = 0; mt < 4; ++mt) {
      m2[mt][0] = (f32x4){b0, b0, b0, b0};
      m2[mt][1] = (f32x4){b1, b1, b1, b1};
    }
  }
  #pragma unroll
  for (int kk = 0; kk < 4; ++kk) {
    half8 n0, n1;
    if (kk < 3) {
      n0 = *(const half8*)(bn2base + (kk + 1) * 4096);
      n1 = *(const half8*)(bn2base + (kk + 1) * 4096 + 128);
    }
    #pragma unroll
    for (int mt = 0; mt < 4; ++mt) {
      half8 a = *(const half8*)&T[(mt * 16 + c) * TS + kk * 32 + q * 8];
      m2[mt][0] = __builtin_amdgcn_mfma_f32_16x16x32_f16(a, d0, m2[mt][0], 0, 0, 0);
      m2[mt][1] = __builtin_amdgcn_mfma_f32_16x16x32_f16(a, d1, m2[mt][1], 0, 0, 0);
    }
    d0 = n0; d1 = n1;
  }
  #pragma unroll
  for (int mt = 0; mt < 4; ++mt)
    #pragma unroll
    for (int r = 0; r < 4; ++r) {
      int g = n0 + mt * 16 + q * 4 + r;
      if (g < N_NODES) {
        float* o = out + (size_t)g * HID + colBase + c;
        o[0]  = m2[mt][0][r];
        o[16] = m2[mt][1][r];
      }
    }
}

extern "C" void kernel_launch(void* const* d_in, const int* in_sizes, int n_in,
                              void* d_out, int out_size, void* d_ws, size_t ws_size,
                              hipStream_t stream) {
  const float* h    = (const float*)d_in[0];
  const int*   eidx = (const int*)d_in[1];
  const float* eattr= (const float*)d_in[2];
  const float* We1  = (const float*)d_in[3];
  const float* be1  = (const float*)d_in[4];
  const float* We2  = (const float*)d_in[5];
  const float* be2  = (const float*)d_in[6];
  const float* Wg   = (const float*)d_in[7];
  const float* bg   = (const float*)d_in[8];
  const float* Wn1  = (const float*)d_in[9];
  const float* bn1  = (const float*)d_in[10];
  const float* Wn2  = (const float*)d_in[11];
  const float* bn2  = (const float*)d_in[12];
  float* out = (float*)d_out;
  char* ws = (char*)d_ws;

  if (ws_size >= CSR_TOTAL) {
    f16* medge = (f16*)(ws + OFF_MEDGE);
    f16* h16   = (f16*)(ws + OFF_H16C);
    f16* Wp    = (f16*)(ws + OFF_WC);
    int* cnt   = (int*)(ws + OFF_CNT);
    int* offs  = (int*)(ws + OFF_OFFS);
    int* cur   = (int*)(ws + OFF_CUR);
    int* pos   = (int*)(ws + OFF_POS);

    pack_weights<<<400, 256, 0, stream>>>(We1, We2, Wn1, Wn2, Wp, cnt);
    convert_hist<<<3125, 256, 0, stream>>>(h, eidx, h16, cnt);
    scan_kernel<<<1, 256, 0, stream>>>(cnt, offs, cur);
    scatter_kernel<<<3125, 256, 0, stream>>>(eidx, cur, pos);
    edge_kernel<<<N_EDGES / 64, 256, 0, stream>>>(h16, eidx, eattr, pos, Wp, be1, be2,
                                                  Wg, bg, nullptr, medge);
    node_kernel_csr<<<(N_NODES + 63) / 64, 256, 0, stream>>>(medge, offs, cnt, h16,
                                                             Wp, bn1, bn2, out);
  } else {
    float* mi  = (float*)(ws + OFF_MI);
    f16*   h16 = (f16*)(ws + OFF_H16);
    f16*   Wp  = (f16*)(ws + OFF_W);

    hipMemsetAsync(mi, 0, (size_t)N_NODES * HID * sizeof(float), stream);
    pack_weights<<<400, 256, 0, stream>>>(We1, We2, Wn1, Wn2, Wp, nullptr);
    convert_hist<<<3125, 256, 0, stream>>>(h, eidx, h16, nullptr);
    edge_kernel<<<N_EDGES / 64, 256, 0, stream>>>(h16, eidx, eattr, nullptr, Wp, be1, be2,
                                                  Wg, bg, mi, nullptr);
    node_kernel<<<(N_NODES + 63) / 64, 256, 0, stream>>>(mi, h16, Wp, bn1, bn2, out);
  }
}

// Round 6
// 468.960 us; speedup vs baseline: 1.1091x; 1.0868x over previous
//
#include <hip/hip_runtime.h>

#define N_NODES 50000
#define N_EDGES 800000
#define HID 128

typedef _Float16 f16;
typedef _Float16 half8 __attribute__((ext_vector_type(8)));
typedef _Float16 half4 __attribute__((ext_vector_type(4)));
typedef _Float16 half2v __attribute__((ext_vector_type(2)));
typedef float f32x4 __attribute__((ext_vector_type(4)));
typedef float f32x2 __attribute__((ext_vector_type(2)));

// ---- CSR-path workspace layout (bytes). mi lives in d_out (f32, 25.6MB). ----
#define OFF_MEDGE  0UL             // 800000*128*2 = 204,800,000 (CSR-slot gated messages)
#define OFF_H16C   204800000UL     // 12,800,000
#define OFF_WC     217600000UL     // packed weights: 204,800
#define OFF_CNT    217804800UL     // 50176*4 = 200,704
#define OFF_OFFS   218005504UL     // 200,704
#define OFF_CUR    218206208UL     // 200,704
#define CSR_TOTAL  218406912UL

// ---- fallback (atomic-path) layout ----
#define OFF_MI   0UL
#define OFF_H16  25600000UL
#define OFF_W    38400000UL

#define WB1 0
#define WB2 36864
#define WN1 53248
#define WN2 86016

#define XS 296   // X tile stride (f16): 128 hdst | 128 hsrc | 24 attr | 8 zero | 8 unused
#define TS 136   // T tile stride (aliased into X buffer)
#define YS 264   // node Y tile stride (256 + pad)

// pack weights into B-fragment layout; also zero cnt (CSR path)
__global__ __launch_bounds__(256) void pack_weights(
    const float* __restrict__ We1, const float* __restrict__ We2,
    const float* __restrict__ Wn1, const float* __restrict__ Wn2,
    f16* __restrict__ W, int* __restrict__ cnt) {
  int i = blockIdx.x * 256 + threadIdx.x;   // 0..102399
  if (cnt && i < 50176) cnt[i] = 0;
  if (i < 36864) {                          // We1 (rows permuted: h first, attr last)
    int j = i & 7, n = (i >> 3) & 127, qk = i >> 10;
    int k = qk * 8 + j;
    float v = 0.f;
    if (k < 256) v = We1[(24 + k) * 128 + n];
    else if (k < 280) v = We1[(k - 256) * 128 + n];
    W[WB1 + i] = (f16)v;
  } else if (i < 53248) {                   // We2
    int l = i - 36864;
    int j = l & 7, n = (l >> 3) & 127, qk = l >> 10;
    W[WB2 + l] = (f16)We2[(qk * 8 + j) * 128 + n];
  } else if (i < 86016) {                   // Wn1
    int l = i - 53248;
    int j = l & 7, n = (l >> 3) & 127, qk = l >> 10;
    W[WN1 + l] = (f16)Wn1[(qk * 8 + j) * 128 + n];
  } else if (i < 102400) {                  // Wn2
    int l = i - 86016;
    int j = l & 7, n = (l >> 3) & 127, qk = l >> 10;
    W[WN2 + l] = (f16)Wn2[(qk * 8 + j) * 128 + n];
  }
}

// h f32 -> f16 (800K threads); fused degree histogram (CSR path)
__global__ __launch_bounds__(256) void convert_hist(
    const float* __restrict__ h, const int* __restrict__ eidx,
    f16* __restrict__ h16, int* __restrict__ cnt) {
  int i = blockIdx.x * 256 + threadIdx.x;   // 0..799999 exactly
  const float4* src = (const float4*)h + (size_t)i * 2;
  float4 a = src[0], b = src[1];
  half8 v = {(f16)a.x, (f16)a.y, (f16)a.z, (f16)a.w,
             (f16)b.x, (f16)b.y, (f16)b.z, (f16)b.w};
  *((half8*)h16 + i) = v;
  if (cnt) atomicAdd(&cnt[eidx[i]], 1);
}

// single-block exclusive scan of 50176 counts -> offs, cur
__global__ __launch_bounds__(256) void scan_kernel(const int* __restrict__ cnt,
                                                   int* __restrict__ offs, int* __restrict__ cur) {
  __shared__ int sb[256];
  int t = threadIdx.x;
  int base = t * 196;               // 256*196 = 50176
  int s = 0;
  for (int k = 0; k < 196; ++k) s += cnt[base + k];
  sb[t] = s;
  __syncthreads();
  for (int off = 1; off < 256; off <<= 1) {
    int v = (t >= off) ? sb[t - off] : 0;
    __syncthreads();
    sb[t] += v;
    __syncthreads();
  }
  int run = sb[t] - s;
  for (int k = 0; k < 196; ++k) {
    int c = cnt[base + k];
    offs[base + k] = run;
    cur[base + k] = run;
    run += c;
  }
}

// ==== edge kernel: natural-order staging; CSR mode claims a slot per row via
//      atomicAdd(cur[dst]) during staging and scatter-stores the 256B row there ====
__global__ __launch_bounds__(256, 4) void edge_kernel(
    const f16* __restrict__ h16, const int* __restrict__ eidx,
    const float* __restrict__ eattr,
    const f16* __restrict__ Wp, const float* __restrict__ be1,
    const float* __restrict__ be2,
    const float* __restrict__ Wg, const float* __restrict__ bg,
    float* __restrict__ mi, f16* __restrict__ medge, int* __restrict__ cur) {
  __shared__ f16 X[64 * XS];
  __shared__ float part[64 * 4];
  __shared__ float eijL[64];
  __shared__ int idxL[64];   // CSR: claimed slot; fallback: dst
  int t = threadIdx.x;
  int e0 = blockIdx.x * 64;

  if (t < 64) {
    int d = eidx[e0 + t];
    idxL[t] = medge ? atomicAdd(&cur[d], 1) : d;
  }
  // ---- stage X: h[dst] (cols 0..127), h[src] (cols 128..255) ----
  {
    int rb = t >> 4, ch = t & 15;
    for (int p = 0; p < 4; ++p) {
      int r = p * 16 + rb;
      int d = eidx[e0 + r];
      int s = eidx[N_EDGES + e0 + r];
      *(uint4*)&X[r * XS + ch * 8]       = *(const uint4*)(h16 + (size_t)d * HID + ch * 8);
      *(uint4*)&X[r * XS + 128 + ch * 8] = *(const uint4*)(h16 + (size_t)s * HID + ch * 8);
    }
  }
  // ---- stage edge_attr (cols 256..279), fully coalesced ----
  for (int i = t; i < 384; i += 256) {
    int el = i / 6, kk = (i % 6) * 4;
    float4 f = *(const float4*)(eattr + (size_t)e0 * 24 + (size_t)i * 4);
    half4 hv = {(f16)f.x, (f16)f.y, (f16)f.z, (f16)f.w};
    *(half4*)&X[el * XS + 256 + kk] = hv;
  }
  if (t < 64) { uint4 z = {0, 0, 0, 0}; *(uint4*)&X[t * XS + 280] = z; }
  __syncthreads();

  int w = t >> 6, lane = t & 63, q = lane >> 4, c = lane & 15;
  int colBase = w * 32;
  const f16* Bp1 = Wp + WB1;
  const f16* Bp2 = Wp + WB2;

  // ---- layer 1 ----
  f32x4 acc[4][2];
  {
    float b0 = be1[colBase + c], b1 = be1[colBase + 16 + c];
    #pragma unroll
    for (int mt = 0; mt < 4; ++mt) {
      acc[mt][0] = (f32x4){b0, b0, b0, b0};
      acc[mt][1] = (f32x4){b1, b1, b1, b1};
    }
  }
  const f16* bp1base = Bp1 + ((size_t)(q * 128 + colBase + c)) * 8;
  half8 bf0 = *(const half8*)(bp1base);
  half8 bf1 = *(const half8*)(bp1base + 128);
  #pragma unroll
  for (int ks = 0; ks < 9; ++ks) {
    half8 nb0, nb1;
    if (ks < 8) {
      nb0 = *(const half8*)(bp1base + (ks + 1) * 4096);
      nb1 = *(const half8*)(bp1base + (ks + 1) * 4096 + 128);
    }
    #pragma unroll
    for (int mt = 0; mt < 4; ++mt) {
      half8 a = *(const half8*)&X[(mt * 16 + c) * XS + ks * 32 + q * 8];
      acc[mt][0] = __builtin_amdgcn_mfma_f32_16x16x32_f16(a, bf0, acc[mt][0], 0, 0, 0);
      acc[mt][1] = __builtin_amdgcn_mfma_f32_16x16x32_f16(a, bf1, acc[mt][1], 0, 0, 0);
    }
    bf0 = nb0; bf1 = nb1;
  }

  const f16* bp2base = Bp2 + ((size_t)(q * 128 + colBase + c)) * 8;
  half8 d0 = *(const half8*)(bp2base);
  half8 d1 = *(const half8*)(bp2base + 128);

  __syncthreads();
  f16* T = X;   // alias
  #pragma unroll
  for (int mt = 0; mt < 4; ++mt)
    #pragma unroll
    for (int nt = 0; nt < 2; ++nt)
      #pragma unroll
      for (int r = 0; r < 4; ++r) {
        float v = acc[mt][nt][r];
        T[(mt * 16 + q * 4 + r) * TS + colBase + nt * 16 + c] = (f16)(v > 0.f ? v : 0.f);
      }
  __syncthreads();

  // ---- layer 2 ----
  f32x4 m2[4][2];
  {
    float b0 = be2[colBase + c], b1 = be2[colBase + 16 + c];
    #pragma unroll
    for (int mt = 0; mt < 4; ++mt) {
      m2[mt][0] = (f32x4){b0, b0, b0, b0};
      m2[mt][1] = (f32x4){b1, b1, b1, b1};
    }
  }
  #pragma unroll
  for (int kk = 0; kk < 4; ++kk) {
    half8 n0, n1;
    if (kk < 3) {
      n0 = *(const half8*)(bp2base + (kk + 1) * 4096);
      n1 = *(const half8*)(bp2base + (kk + 1) * 4096 + 128);
    }
    #pragma unroll
    for (int mt = 0; mt < 4; ++mt) {
      half8 a = *(const half8*)&T[(mt * 16 + c) * TS + kk * 32 + q * 8];
      m2[mt][0] = __builtin_amdgcn_mfma_f32_16x16x32_f16(a, d0, m2[mt][0], 0, 0, 0);
      m2[mt][1] = __builtin_amdgcn_mfma_f32_16x16x32_f16(a, d1, m2[mt][1], 0, 0, 0);
    }
    d0 = n0; d1 = n1;
  }

  // ---- relu + gate ----
  float wg0 = Wg[colBase + c], wg1 = Wg[colBase + 16 + c];
  float pd[4][4];
  #pragma unroll
  for (int mt = 0; mt < 4; ++mt)
    #pragma unroll
    for (int r = 0; r < 4; ++r) {
      float v0 = m2[mt][0][r]; v0 = v0 > 0.f ? v0 : 0.f; m2[mt][0][r] = v0;
      float v1 = m2[mt][1][r]; v1 = v1 > 0.f ? v1 : 0.f; m2[mt][1][r] = v1;
      pd[mt][r] = v0 * wg0 + v1 * wg1;
    }
  #pragma unroll
  for (int off = 1; off < 16; off <<= 1)
    #pragma unroll
    for (int mt = 0; mt < 4; ++mt)
      #pragma unroll
      for (int r = 0; r < 4; ++r)
        pd[mt][r] += __shfl_xor(pd[mt][r], off, 64);
  if (c == 0)
    #pragma unroll
    for (int mt = 0; mt < 4; ++mt)
      #pragma unroll
      for (int r = 0; r < 4; ++r)
        part[(mt * 16 + q * 4 + r) * 4 + w] = pd[mt][r];
  __syncthreads();
  if (t < 64) {
    float s = part[t * 4] + part[t * 4 + 1] + part[t * 4 + 2] + part[t * 4 + 3] + bg[0];
    eijL[t] = 1.f / (1.f + __expf(-s));
  }
  __syncthreads();

  if (medge) {
    #pragma unroll
    for (int mt = 0; mt < 4; ++mt)
      #pragma unroll
      for (int r = 0; r < 4; ++r) {
        int el = mt * 16 + q * 4 + r;
        float ev = eijL[el];
        T[el * TS + colBase + c]      = (f16)(m2[mt][0][r] * ev);
        T[el * TS + colBase + 16 + c] = (f16)(m2[mt][1][r] * ev);
      }
    __syncthreads();
    int r = t >> 2, p = t & 3;
    uint4* dst = (uint4*)(medge + (size_t)idxL[r] * HID + p * 32);
    const uint4* s = (const uint4*)&T[r * TS + p * 32];
    dst[0] = s[0]; dst[1] = s[1]; dst[2] = s[2]; dst[3] = s[3];
  } else {
    #pragma unroll
    for (int mt = 0; mt < 4; ++mt)
      #pragma unroll
      for (int r = 0; r < 4; ++r) {
        int el = mt * 16 + q * 4 + r;
        float ev = eijL[el];
        float* base = mi + (size_t)idxL[el] * HID + colBase + c;
        atomicAdd(base,      m2[mt][0][r] * ev);
        atomicAdd(base + 16, m2[mt][1][r] * ev);
      }
  }
}

// ==== seg-sum: one WAVE per node; lane l owns cols [2l,2l+1]. Every iteration is a
//      fully-coalesced 256B wave read of consecutive memory; uniform trip count. ====
__global__ __launch_bounds__(256) void segsum_kernel(
    const f16* __restrict__ medge, const int* __restrict__ offs,
    const int* __restrict__ cnt, float* __restrict__ mi) {
  int t = threadIdx.x;
  int g = blockIdx.x * 4 + (t >> 6);      // 12500 blocks * 4 waves = 50000 nodes
  int l = t & 63;
  int start = offs[g], deg = cnt[g];
  const f16* base = medge + (size_t)start * HID + 2 * l;
  float ax = 0.f, ay = 0.f;
  #pragma unroll 4
  for (int i = 0; i < deg; ++i) {
    half2v v = *(const half2v*)(base + (size_t)i * HID);
    ax += (float)v[0]; ay += (float)v[1];
  }
  f32x2 o = {ax, ay};
  *(f32x2*)(mi + (size_t)g * HID + 2 * l) = o;
}

// ==== node MLP kernel: reads f32 mi + h16, writes out. mi MAY alias out:
//      each block reads only its own rows (before barrier) and writes them after. ====
__global__ __launch_bounds__(256, 4) void node_kernel(
    const float* mi, const f16* __restrict__ h16,
    const f16* __restrict__ Wp, const float* __restrict__ bn1,
    const float* __restrict__ bn2, float* out) {
  __shared__ f16 Y[64 * YS];
  int t = threadIdx.x;
  int n0 = blockIdx.x * 64;
  {
    int rb = t >> 4, ch = t & 15;
    for (int p = 0; p < 4; ++p) {
      int r = p * 16 + rb;
      int g = n0 + r; if (g >= N_NODES) g = N_NODES - 1;
      const float4* s = (const float4*)(mi + (size_t)g * HID + ch * 8);
      float4 a = s[0], b = s[1];
      half8 v = {(f16)a.x, (f16)a.y, (f16)a.z, (f16)a.w,
                 (f16)b.x, (f16)b.y, (f16)b.z, (f16)b.w};
      *(half8*)&Y[r * YS + ch * 8] = v;
      *(uint4*)&Y[r * YS + 128 + ch * 8] = *(const uint4*)(h16 + (size_t)g * HID + ch * 8);
    }
  }
  __syncthreads();
  int w = t >> 6, lane = t & 63, q = lane >> 4, c = lane & 15;
  int colBase = w * 32;
  const f16* BN1 = Wp + WN1;
  const f16* BN2 = Wp + WN2;
  f32x4 acc[4][2];
  {
    float b0 = bn1[colBase + c], b1 = bn1[colBase + 16 + c];
    #pragma unroll
    for (int mt = 0; mt < 4; ++mt) {
      acc[mt][0] = (f32x4){b0, b0, b0, b0};
      acc[mt][1] = (f32x4){b1, b1, b1, b1};
    }
  }
  const f16* bn1base = BN1 + ((size_t)(q * 128 + colBase + c)) * 8;
  half8 bf0 = *(const half8*)(bn1base);
  half8 bf1 = *(const half8*)(bn1base + 128);
  #pragma unroll
  for (int ks = 0; ks < 8; ++ks) {
    half8 nb0, nb1;
    if (ks < 7) {
      nb0 = *(const half8*)(bn1base + (ks + 1) * 4096);
      nb1 = *(const half8*)(bn1base + (ks + 1) * 4096 + 128);
    }
    #pragma unroll
    for (int mt = 0; mt < 4; ++mt) {
      half8 a = *(const half8*)&Y[(mt * 16 + c) * YS + ks * 32 + q * 8];
      acc[mt][0] = __builtin_amdgcn_mfma_f32_16x16x32_f16(a, bf0, acc[mt][0], 0, 0, 0);
      acc[mt][1] = __builtin_amdgcn_mfma_f32_16x16x32_f16(a, bf1, acc[mt][1], 0, 0, 0);
    }
    bf0 = nb0; bf1 = nb1;
  }
  const f16* bn2base = BN2 + ((size_t)(q * 128 + colBase + c)) * 8;
  half8 d0 = *(const half8*)(bn2base);
  half8 d1 = *(const half8*)(bn2base + 128);
  __syncthreads();
  f16* T = Y;
  #pragma unroll
  for (int mt = 0; mt < 4; ++mt)
    #pragma unroll
    for (int nt = 0; nt < 2; ++nt)
      #pragma unroll
      for (int r = 0; r < 4; ++r) {
        float v = acc[mt][nt][r];
        T[(mt * 16 + q * 4 + r) * TS + colBase + nt * 16 + c] = (f16)(v > 0.f ? v : 0.f);
      }
  __syncthreads();
  f32x4 m2[4][2];
  {
    float b0 = bn2[colBase + c], b1 = bn2[colBase + 16 + c];
    #pragma unroll
    for (int mt = 0; mt < 4; ++mt) {
      m2[mt][0] = (f32x4){b0, b0, b0, b0};
      m2[mt][1] = (f32x4){b1, b1, b1, b1};
    }
  }
  #pragma unroll
  for (int kk = 0; kk < 4; ++kk) {
    half8 n0, n1;
    if (kk < 3) {
      n0 = *(const half8*)(bn2base + (kk + 1) * 4096);
      n1 = *(const half8*)(bn2base + (kk + 1) * 4096 + 128);
    }
    #pragma unroll
    for (int mt = 0; mt < 4; ++mt) {
      half8 a = *(const half8*)&T[(mt * 16 + c) * TS + kk * 32 + q * 8];
      m2[mt][0] = __builtin_amdgcn_mfma_f32_16x16x32_f16(a, d0, m2[mt][0], 0, 0, 0);
      m2[mt][1] = __builtin_amdgcn_mfma_f32_16x16x32_f16(a, d1, m2[mt][1], 0, 0, 0);
    }
    d0 = n0; d1 = n1;
  }
  #pragma unroll
  for (int mt = 0; mt < 4; ++mt)
    #pragma unroll
    for (int r = 0; r < 4; ++r) {
      int g = n0 + mt * 16 + q * 4 + r;
      if (g < N_NODES) {
        float* o = out + (size_t)g * HID + colBase + c;
        o[0]  = m2[mt][0][r];
        o[16] = m2[mt][1][r];
      }
    }
}

extern "C" void kernel_launch(void* const* d_in, const int* in_sizes, int n_in,
                              void* d_out, int out_size, void* d_ws, size_t ws_size,
                              hipStream_t stream) {
  const float* h    = (const float*)d_in[0];
  const int*   eidx = (const int*)d_in[1];
  const float* eattr= (const float*)d_in[2];
  const float* We1  = (const float*)d_in[3];
  const float* be1  = (const float*)d_in[4];
  const float* We2  = (const float*)d_in[5];
  const float* be2  = (const float*)d_in[6];
  const float* Wg   = (const float*)d_in[7];
  const float* bg   = (const float*)d_in[8];
  const float* Wn1  = (const float*)d_in[9];
  const float* bn1  = (const float*)d_in[10];
  const float* Wn2  = (const float*)d_in[11];
  const float* bn2  = (const float*)d_in[12];
  float* out = (float*)d_out;
  char* ws = (char*)d_ws;

  if (ws_size >= CSR_TOTAL) {
    f16* medge = (f16*)(ws + OFF_MEDGE);
    f16* h16   = (f16*)(ws + OFF_H16C);
    f16* Wp    = (f16*)(ws + OFF_WC);
    int* cnt   = (int*)(ws + OFF_CNT);
    int* offs  = (int*)(ws + OFF_OFFS);
    int* cur   = (int*)(ws + OFF_CUR);
    float* mi  = out;   // alias: seg-sum fills it, node MLP consumes + overwrites per-block

    pack_weights<<<400, 256, 0, stream>>>(We1, We2, Wn1, Wn2, Wp, cnt);
    convert_hist<<<3125, 256, 0, stream>>>(h, eidx, h16, cnt);
    scan_kernel<<<1, 256, 0, stream>>>(cnt, offs, cur);
    edge_kernel<<<N_EDGES / 64, 256, 0, stream>>>(h16, eidx, eattr, Wp, be1, be2,
                                                  Wg, bg, nullptr, medge, cur);
    segsum_kernel<<<N_NODES / 4, 256, 0, stream>>>(medge, offs, cnt, mi);
    node_kernel<<<(N_NODES + 63) / 64, 256, 0, stream>>>(mi, h16, Wp, bn1, bn2, out);
  } else {
    float* mi  = (float*)(ws + OFF_MI);
    f16*   h16 = (f16*)(ws + OFF_H16);
    f16*   Wp  = (f16*)(ws + OFF_W);

    hipMemsetAsync(mi, 0, (size_t)N_NODES * HID * sizeof(float), stream);
    pack_weights<<<400, 256, 0, stream>>>(We1, We2, Wn1, Wn2, Wp, nullptr);
    convert_hist<<<3125, 256, 0, stream>>>(h, eidx, h16, nullptr);
    edge_kernel<<<N_EDGES / 64, 256, 0, stream>>>(h16, eidx, eattr, Wp, be1, be2,
                                                  Wg, bg, mi, nullptr, nullptr);
    node_kernel<<<(N_NODES + 63) / 64, 256, 0, stream>>>(mi, h16, Wp, bn1, bn2, out);
  }
}